// Round 6
// baseline (195.005 us; speedup 1.0000x reference)
//
#include <hip/hip_runtime.h>
#include <hip/hip_bf16.h>

#define IN_DIM 128
#define HID_DIM 64
#define OUT_DIM 16

// Stripe/bin geometry: 128 nodes per stripe
#define SSHIFT 7
#define SMASK 127
// Edge chunking for passes A/C: 245 blocks -> all CUs busy
#define CHUNK 4096
#define CBLK 256

// bf16 helpers: round-to-nearest-even pack, bit-shift unpack
static __device__ __forceinline__ unsigned short f2bf(float f) {
    unsigned u = __float_as_uint(f);
    unsigned r = u + 0x7fffu + ((u >> 16) & 1u);
    return (unsigned short)(r >> 16);
}
static __device__ __forceinline__ unsigned packbf2(float a, float b) {
    return (unsigned)f2bf(a) | ((unsigned)f2bf(b) << 16);
}
static __device__ __forceinline__ float bflo(unsigned v) { return __uint_as_float(v << 16); }
static __device__ __forceinline__ float bfhi(unsigned v) { return __uint_as_float(v & 0xffff0000u); }

// ---------------------------------------------------------------------------
// passA: per-block per-stripe histogram (LDS only, no global atomics)
// ---------------------------------------------------------------------------
__global__ __launch_bounds__(CBLK) void passA(const int* __restrict__ dst,
                                              int* __restrict__ cm,
                                              int E, int NS, int NSP) {
    __shared__ int cnt[512];
    int t = threadIdx.x;
    for (int s = t; s < NS; s += CBLK) cnt[s] = 0;
    __syncthreads();
    int base = blockIdx.x * CHUNK;
    #pragma unroll 4
    for (int k = 0; k < CHUNK; k += CBLK) {
        int i = base + k + t;
        if (i < E) atomicAdd(&cnt[dst[i] >> SSHIFT], 1);
    }
    __syncthreads();
    for (int s = t; s < NS; s += CBLK) cm[blockIdx.x * NSP + s] = cnt[s];
}

// ---------------------------------------------------------------------------
// passB1: per-stripe exclusive scan over blocks; tot[s] = sum. B <= 256.
// ---------------------------------------------------------------------------
__global__ __launch_bounds__(256) void passB1(int* __restrict__ cm, int* __restrict__ tot,
                                              int B, int NSP) {
    __shared__ int sv[256];
    int t = threadIdx.x, s = blockIdx.x;
    int v = (t < B) ? cm[t * NSP + s] : 0;
    sv[t] = v;
    __syncthreads();
    for (int off = 1; off < 256; off <<= 1) {
        int tmp = (t >= off) ? sv[t - off] : 0;
        __syncthreads();
        sv[t] += tmp;
        __syncthreads();
    }
    if (t < B) cm[t * NSP + s] = sv[t] - v;
    if (t == 255) tot[s] = sv[255];
}

// ---------------------------------------------------------------------------
// passB2: exclusive scan of stripe totals -> stripe base offsets (NS <= 512).
// Also zeroes the dummy row N of h2u (used as zero-pad by agg2 tails).
// ---------------------------------------------------------------------------
__global__ __launch_bounds__(512) void passB2(const int* __restrict__ tot,
                                              int* __restrict__ sbase,
                                              unsigned* __restrict__ h2u_dummy,
                                              int NS) {
    __shared__ int sv[512];
    int t = threadIdx.x;
    int v = (t < NS) ? tot[t] : 0;
    sv[t] = v;
    __syncthreads();
    for (int off = 1; off < 512; off <<= 1) {
        int tmp = (t >= off) ? sv[t - off] : 0;
        __syncthreads();
        sv[t] += tmp;
        __syncthreads();
    }
    if (t < NS) sbase[t] = sv[t] - v;
    if (t >= 504) h2u_dummy[t - 504] = 0u;    // 8 uints = h2u row N
}

// ---------------------------------------------------------------------------
// passC: bucket edges by stripe; LDS cursors; packed (dl<<17)|src
// ---------------------------------------------------------------------------
__global__ __launch_bounds__(CBLK) void passC(const int* __restrict__ src,
                                              const int* __restrict__ dst,
                                              const int* __restrict__ cm,
                                              const int* __restrict__ sbase,
                                              int* __restrict__ eb,
                                              int E, int NS, int NSP) {
    __shared__ int cur[512];
    int t = threadIdx.x, b = blockIdx.x;
    for (int s = t; s < NS; s += CBLK) cur[s] = sbase[s] + cm[b * NSP + s];
    __syncthreads();
    int base = b * CHUNK;
    #pragma unroll 4
    for (int k = 0; k < CHUNK; k += CBLK) {
        int i = base + k + t;
        if (i < E) {
            int d = dst[i];
            int s = d >> SSHIFT;
            int pos = atomicAdd(&cur[s], 1);
            eb[pos] = src[i] | ((d & SMASK) << 17);
        }
    }
}

// ---------------------------------------------------------------------------
// passD: per-stripe LDS counting sort -> exact CSR + row_ptr + dinv.
// ---------------------------------------------------------------------------
__global__ __launch_bounds__(256) void passD(const int* __restrict__ eb,
                                             const int* __restrict__ sbase,
                                             const int* __restrict__ tot,
                                             int* __restrict__ csr_src,
                                             int* __restrict__ row_ptr,
                                             float* __restrict__ dinv,
                                             int N, int E, int NS) {
    __shared__ int deg[128], incl[128], cur[128];
    int s = blockIdx.x, t = threadIdx.x;
    if (t < 128) deg[t] = 0;
    __syncthreads();
    int b0 = sbase[s], cnt = tot[s];
    for (int k = t; k < cnt; k += 256) atomicAdd(&deg[eb[b0 + k] >> 17], 1);
    __syncthreads();
    if (t < 128) incl[t] = deg[t];
    __syncthreads();
    for (int off = 1; off < 128; off <<= 1) {
        int tmp = 0;
        if (t < 128 && t >= off) tmp = incl[t - off];
        __syncthreads();
        if (t < 128) incl[t] += tmp;
        __syncthreads();
    }
    if (t < 128) {
        int loff = incl[t] - deg[t];
        cur[t] = b0 + loff;
        int n = (s << SSHIFT) + t;
        if (n < N) {
            row_ptr[n] = b0 + loff;
            dinv[n] = rsqrtf((float)(deg[t] + 1));
        }
    }
    if (s == NS - 1 && t == 0) row_ptr[N] = E;
    __syncthreads();
    for (int k = t; k < cnt; k += 256) {
        int v = eb[b0 + k];
        int dl = v >> 17;
        int p = atomicAdd(&cur[dl], 1);
        csr_src[p] = v & 0x1FFFF;
    }
}

// ---------------------------------------------------------------------------
// GEMM1: h1 = bf16( (x @ W1) * dinv[n] ), row = 32 uints. Row N = zeros (dummy).
// ---------------------------------------------------------------------------
__global__ __launch_bounds__(256) void gemm1_kernel(const float* __restrict__ x,
                                                    const float* __restrict__ W1,
                                                    const float* __restrict__ dinv,
                                                    unsigned* __restrict__ h1u, int N) {
    __shared__ __align__(16) float sW[IN_DIM * HID_DIM];   // 32 KB
    __shared__ __align__(16) float sx[16 * IN_DIM];        // 8 KB
    int t = threadIdx.x;
    int node0 = blockIdx.x * 16;

    const float4* W4  = (const float4*)W1;
    float4*       sW4 = (float4*)sW;
    for (int i = t; i < (IN_DIM * HID_DIM) / 4; i += 256) sW4[i] = W4[i];

    const float4* x4  = (const float4*)x;
    float4*       sx4 = (float4*)sx;
    for (int i = t; i < (16 * IN_DIM) / 4; i += 256) {
        int r = i >> 5, c = i & 31;
        int n = node0 + r; if (n >= N) n = 0;   // clamp; dummy row gets dn=0
        sx4[(r << 5) + c] = x4[(size_t)n * 32 + c];
    }
    __syncthreads();

    int ln = t >> 4, jj = t & 15;
    int n = node0 + ln;
    float4 acc = {0.f, 0.f, 0.f, 0.f};
    const float* xr = sx + ln * IN_DIM;
    #pragma unroll 4
    for (int k = 0; k < IN_DIM; ++k) {
        float  xk = xr[k];
        float4 wv = ((const float4*)(sW + k * HID_DIM))[jj];
        acc.x += xk * wv.x; acc.y += xk * wv.y; acc.z += xk * wv.z; acc.w += xk * wv.w;
    }
    if (n <= N) {
        float dn = (n < N) ? dinv[n] : 0.f;     // row N -> zeros
        uint2 pv;
        pv.x = packbf2(acc.x * dn, acc.y * dn);
        pv.y = packbf2(acc.z * dn, acc.w * dn);
        ((uint2*)(h1u + (size_t)n * 32))[jj] = pv;
    }
}

// ---------------------------------------------------------------------------
// Fused agg1 + gemm2: one wave per node. lane = (es 0..7, dg 0..7).
// Gather phase: uint4/lane -> 8 edge rows per load instruction; indices via
// one coalesced load + __shfl. After xor-reduce every lane holds the full
// 8-dim slice a0..7 for dims 8dg..8dg+7. Epilogue: r = relu(dn*a + b1) in
// fp32, then h2[n][2es,2es+1] = dn * (r @ W2 cols) via LDS-staged W2 and
// xor-reduce over dg. Writes ONLY h2u (pre-scaled by dinv[n]); h1a never
// materialized.
// ---------------------------------------------------------------------------
__global__ __launch_bounds__(256) void agg1_kernel(const unsigned* __restrict__ h1u,
                                                   const int* __restrict__ row_ptr,
                                                   const int* __restrict__ csr_src,
                                                   const float* __restrict__ dinv,
                                                   const float* __restrict__ b1,
                                                   const float* __restrict__ W2,
                                                   unsigned* __restrict__ h2u, int N) {
    __shared__ __align__(16) float sW[HID_DIM * OUT_DIM];  // 4 KB: W2 [64][16]
    int t = threadIdx.x;
    ((float4*)sW)[t] = ((const float4*)W2)[t];             // 256 float4
    __syncthreads();

    int n = blockIdx.x * 4 + (t >> 6);
    if (n >= N) return;
    int lane = t & 63;
    int es = lane >> 3;        // edge slot 0..7  (also output col pair 2es,2es+1)
    int dg = lane & 7;         // dim group: uint4 = dims 8dg..8dg+7

    int e0 = row_ptr[n], e1 = row_ptr[n + 1];
    const uint4* rb = (const uint4*)h1u;     // row = 8 uint4

    float a0 = 0.f, a1 = 0.f, a2 = 0.f, a3 = 0.f,
          a4 = 0.f, a5 = 0.f, a6 = 0.f, a7 = 0.f;

    for (int base = e0 - 1; base < e1; base += 64) {
        int idx = base + lane;
        int sld = N;
        if (idx == e0 - 1) sld = n;              // self loop item
        else if (idx < e1) sld = csr_src[idx];   // predicated coalesced load
        int lim = e1 - base;                     // valid items this chunk (>=1)
        int nr = (lim + 7) >> 3;                 // rounds of 8
        nr = (nr + 1) & ~1;                      // even # rounds (extras hit row N)
        for (int r = 0; r < nr; r += 2) {
            int sA = __shfl(sld, (r << 3) + es);
            int sB = __shfl(sld, ((r + 1) << 3) + es);
            uint4 vA = rb[(size_t)sA * 8 + dg];
            uint4 vB = rb[(size_t)sB * 8 + dg];
            a0 += bflo(vA.x) + bflo(vB.x);
            a1 += bfhi(vA.x) + bfhi(vB.x);
            a2 += bflo(vA.y) + bflo(vB.y);
            a3 += bfhi(vA.y) + bfhi(vB.y);
            a4 += bflo(vA.z) + bflo(vB.z);
            a5 += bfhi(vA.z) + bfhi(vB.z);
            a6 += bflo(vA.w) + bflo(vB.w);
            a7 += bfhi(vA.w) + bfhi(vB.w);
        }
    }
    // reduce over edge slots (es stride 8 -> xor 8,16,32); all lanes get sums
    #pragma unroll
    for (int m = 8; m <= 32; m <<= 1) {
        a0 += __shfl_xor(a0, m); a1 += __shfl_xor(a1, m);
        a2 += __shfl_xor(a2, m); a3 += __shfl_xor(a3, m);
        a4 += __shfl_xor(a4, m); a5 += __shfl_xor(a5, m);
        a6 += __shfl_xor(a6, m); a7 += __shfl_xor(a7, m);
    }
    // epilogue on ALL lanes: h1a slice in fp32
    float dn = dinv[n];
    float4 bA = ((const float4*)b1)[2 * dg];
    float4 bB = ((const float4*)b1)[2 * dg + 1];
    float r0 = fmaxf(fmaf(dn, a0, bA.x), 0.f);
    float r1 = fmaxf(fmaf(dn, a1, bA.y), 0.f);
    float r2 = fmaxf(fmaf(dn, a2, bA.z), 0.f);
    float r3 = fmaxf(fmaf(dn, a3, bA.w), 0.f);
    float r4 = fmaxf(fmaf(dn, a4, bB.x), 0.f);
    float r5 = fmaxf(fmaf(dn, a5, bB.y), 0.f);
    float r6 = fmaxf(fmaf(dn, a6, bB.z), 0.f);
    float r7 = fmaxf(fmaf(dn, a7, bB.w), 0.f);

    // fused gemm2: lane (es,dg) partials for cols j0=2es, j1=2es+1 over dims 8dg..8dg+7
    const float* wrow = sW + (8 * dg) * OUT_DIM + 2 * es;
    float p0 = 0.f, p1 = 0.f;
    #pragma unroll
    for (int i = 0; i < 8; ++i) {
        float2 wv = *(const float2*)(wrow + i * OUT_DIM);
        float ri = (i == 0) ? r0 : (i == 1) ? r1 : (i == 2) ? r2 : (i == 3) ? r3
                 : (i == 4) ? r4 : (i == 5) ? r5 : (i == 6) ? r6 : r7;
        p0 = fmaf(ri, wv.x, p0);
        p1 = fmaf(ri, wv.y, p1);
    }
    // reduce over dg (low 3 lane bits)
    #pragma unroll
    for (int m = 1; m <= 4; m <<= 1) {
        p0 += __shfl_xor(p0, m);
        p1 += __shfl_xor(p1, m);
    }
    if (dg == 0) {
        // store pre-scaled by dinv[n] for agg2
        h2u[(size_t)n * 8 + es] = packbf2(p0 * dn, p1 * dn);
    }
}

// ---------------------------------------------------------------------------
// Aggregation layer 2: one wave per node. lane = (es 0..15, dg 0..3).
// uint2 per lane (4 bf16 dims) -> one load instruction = 16 edge rows.
// h2u (1.6 MB) is L2-resident. out = dinv[n]*sum + b2, fp32.
// ---------------------------------------------------------------------------
__global__ __launch_bounds__(256) void agg2_kernel(const unsigned* __restrict__ h2u,
                                                   const int* __restrict__ row_ptr,
                                                   const int* __restrict__ csr_src,
                                                   const float* __restrict__ dinv,
                                                   const float* __restrict__ b2,
                                                   float* __restrict__ out, int N) {
    int t = threadIdx.x;
    int n = blockIdx.x * 4 + (t >> 6);
    if (n >= N) return;
    int lane = t & 63;
    int es = lane >> 2;        // edge slot 0..15
    int dg = lane & 3;         // dim group: uint2 = dims 4dg..4dg+3

    int e0 = row_ptr[n], e1 = row_ptr[n + 1];
    const uint2* rb = (const uint2*)h2u;     // row = 4 uint2

    float a0 = 0.f, a1 = 0.f, a2 = 0.f, a3 = 0.f;

    for (int base = e0 - 1; base < e1; base += 64) {
        int idx = base + lane;
        int sld = N;
        if (idx == e0 - 1) sld = n;
        else if (idx < e1) sld = csr_src[idx];
        int lim = e1 - base;
        int nr = (lim + 15) >> 4;                // rounds of 16
        nr = (nr + 1) & ~1;                      // even (extras hit row N)
        for (int r = 0; r < nr; r += 2) {
            int sA = __shfl(sld, (r << 4) + es);
            int sB = __shfl(sld, ((r + 1) << 4) + es);
            uint2 vA = rb[(size_t)sA * 4 + dg];
            uint2 vB = rb[(size_t)sB * 4 + dg];
            a0 += bflo(vA.x) + bflo(vB.x);
            a1 += bfhi(vA.x) + bfhi(vB.x);
            a2 += bflo(vA.y) + bflo(vB.y);
            a3 += bfhi(vA.y) + bfhi(vB.y);
        }
    }
    // reduce over edge slots (es stride 4 -> xor 4,8,16,32)
    #pragma unroll
    for (int m = 4; m <= 32; m <<= 1) {
        a0 += __shfl_xor(a0, m); a1 += __shfl_xor(a1, m);
        a2 += __shfl_xor(a2, m); a3 += __shfl_xor(a3, m);
    }
    if (es == 0) {
        float dn = dinv[n];
        float4 bb = ((const float4*)b2)[dg];
        float4 r;
        r.x = fmaf(dn, a0, bb.x);
        r.y = fmaf(dn, a1, bb.y);
        r.z = fmaf(dn, a2, bb.z);
        r.w = fmaf(dn, a3, bb.w);
        ((float4*)out)[(size_t)n * 4 + dg] = r;
    }
}

// ---------------------------------------------------------------------------
// Launch
// ---------------------------------------------------------------------------
extern "C" void kernel_launch(void* const* d_in, const int* in_sizes, int n_in,
                              void* d_out, int out_size, void* d_ws, size_t ws_size,
                              hipStream_t stream) {
    const float* x  = (const float*)d_in[0];
    const int*   ei = (const int*)d_in[1];
    const float* W1 = (const float*)d_in[2];
    const float* b1 = (const float*)d_in[3];
    const float* W2 = (const float*)d_in[4];
    const float* b2 = (const float*)d_in[5];
    float* out = (float*)d_out;

    const int N = in_sizes[0] / IN_DIM;   // 50000
    const int E = in_sizes[1] / 2;        // 1000000
    const int* src = ei;
    const int* dst = ei + E;

    const int NS  = (N + SMASK) >> SSHIFT;       // 391 stripes
    const int NSP = NS + 1;
    const int BC  = (E + CHUNK - 1) / CHUNK;     // 245 chunks (<= 256)

    char* w = (char*)d_ws;
    auto alloc = [&](size_t bytes) -> void* {
        void* p = (void*)w;
        w += (bytes + 255) & ~(size_t)255;
        return p;
    };
    int*      cm      = (int*)     alloc((size_t)256 * NSP * 4);
    int*      tot     = (int*)     alloc((size_t)NS * 4);
    int*      sbase   = (int*)     alloc((size_t)NS * 4);
    int*      eb      = (int*)     alloc((size_t)E * 4);
    int*      csr_src = (int*)     alloc((size_t)E * 4);
    int*      row_ptr = (int*)     alloc((size_t)(N + 1) * 4);
    float*    dinv    = (float*)   alloc((size_t)N * 4);
    unsigned* h1u     = (unsigned*)alloc((size_t)(N + 1) * 32 * 4);  // bf16 [N+1][64]
    unsigned* h2u     = (unsigned*)alloc((size_t)(N + 1) * 8 * 4);   // bf16 [N+1][16]

    const int GB = (N + 16) / 16;    // covers rows 0..N (incl. dummy)
    const int AB = (N + 3) / 4;      // 4 nodes (waves) per block

    passA <<<BC, CBLK, 0, stream>>>(dst, cm, E, NS, NSP);
    passB1<<<NS, 256,  0, stream>>>(cm, tot, BC, NSP);
    passB2<<<1,  512,  0, stream>>>(tot, sbase, h2u + (size_t)N * 8, NS);
    passC <<<BC, CBLK, 0, stream>>>(src, dst, cm, sbase, eb, E, NS, NSP);
    passD <<<NS, 256,  0, stream>>>(eb, sbase, tot, csr_src, row_ptr, dinv, N, E, NS);

    gemm1_kernel<<<GB, 256, 0, stream>>>(x, W1, dinv, h1u, N);
    agg1_kernel<<<AB, 256, 0, stream>>>(h1u, row_ptr, csr_src, dinv, b1, W2, h2u, N);
    agg2_kernel<<<AB, 256, 0, stream>>>(h2u, row_ptr, csr_src, dinv, b2, out, N);
}